// Round 1
// baseline (486.387 us; speedup 1.0000x reference)
//
#include <hip/hip_runtime.h>
#include <stdint.h>

typedef unsigned int u32;
typedef unsigned short u16;

// ---------------- problem constants ----------------
#define NU 100000
#define NB 50000
#define NC 1000

#define E_TOT 2000000
#define G_TOT 351000

#define KU 384
#define KB 512
#define KC 256
#define SELF_U 256
#define SELF_B 384
#define SELF_C 128
#define MU_PAD 100096
#define MB_PAD 50176
#define MC_PAD 1024

#define CAP 4096
#define NBKT 1034
#define NBKT_PAD 1280

#define PULL_GRID 2048

// ---------------- helpers ----------------
__device__ __forceinline__ u16 f2bf(float f) {
  u32 u = __float_as_uint(f);
  u += 0x7fffu + ((u >> 16) & 1u);
  return (u16)(u >> 16);
}
__device__ __forceinline__ float bf_lo(u32 v) { return __uint_as_float(v << 16); }
__device__ __forceinline__ float bf_hi(u32 v) { return __uint_as_float(v & 0xffff0000u); }

struct EdgePtrs { const int* p[6]; };
struct PullMeta {
  const u16* src[6];
  u16* dst[6];
  int srcK[6];
  int dstK[6];
};

#define REL_TABLES                                                              \
  constexpr int EB[7] = {0, 500000, 1000000, 1300000, 1600000, 1800000, 2000000}; \
  constexpr int EC[6] = {500000, 500000, 300000, 300000, 200000, 200000};         \
  constexpr int GB[6] = {0, 50000, 150000, 250000, 300000, 301000};               \
  constexpr int SH[6] = {8, 9, 9, 9, 2, 9};                                       \
  constexpr int BKB[7] = {0, 196, 392, 588, 686, 936, 1034};                      \
  constexpr int ND[6] = {50000, 100000, 100000, 50000, 1000, 50000};

// ---------------- CSR build ----------------
__global__ __launch_bounds__(256) void bhist_kernel(EdgePtrs ep, int* __restrict__ bktcnt) {
  REL_TABLES
  __shared__ int h[NBKT];
  const int tid = threadIdx.x;
  for (int j = tid; j < NBKT; j += 256) h[j] = 0;
  __syncthreads();
  const int ebase = blockIdx.x * 16384;
  const int eend = min(ebase + 16384, E_TOT);
  for (int e = ebase + tid; e < eend; e += 256) {
    int r = 0;
#pragma unroll
    for (int i = 1; i < 6; ++i) r += (e >= EB[i]);
    int dst = ep.p[r][EC[r] + e - EB[r]];
    atomicAdd(&h[BKB[r] + (dst >> SH[r])], 1);
  }
  __syncthreads();
  for (int j = tid; j < NBKT; j += 256)
    if (h[j]) atomicAdd(&bktcnt[j], h[j]);
}

__global__ __launch_bounds__(256) void bscan_kernel(const int* __restrict__ bktcnt,
                                                    int* __restrict__ bktbase,
                                                    int* __restrict__ gcursor,
                                                    int* __restrict__ row_ptr) {
  __shared__ int scanbuf[256];
  int tid = threadIdx.x;
  int c[5];
  int own = 0;
  int j0 = tid * 5;
#pragma unroll
  for (int j = 0; j < 5; ++j) {
    int b = j0 + j;
    c[j] = (b < NBKT) ? bktcnt[b] : 0;
    own += c[j];
  }
  scanbuf[tid] = own;
  __syncthreads();
  for (int o = 1; o < 256; o <<= 1) {
    int v = (tid >= o) ? scanbuf[tid - o] : 0;
    __syncthreads();
    scanbuf[tid] += v;
    __syncthreads();
  }
  int run = scanbuf[tid] - own;
#pragma unroll
  for (int j = 0; j < 5; ++j) {
    int b = j0 + j;
    if (b < NBKT) {
      bktbase[b] = run;
      gcursor[b] = run;
      run += c[j];
    }
  }
  if (tid == 255) {
    bktbase[NBKT] = E_TOT;
    row_ptr[G_TOT] = E_TOT;
  }
}

__global__ __launch_bounds__(256) void bucket1_kernel(EdgePtrs ep, int* __restrict__ gcursor,
                                                      u32* __restrict__ colbuf2) {
  REL_TABLES
  __shared__ int hist[NBKT_PAD];
  __shared__ int off[NBKT_PAD];
  __shared__ int cur[NBKT_PAD];
  __shared__ u32 vals[CAP];
  __shared__ u16 bks[CAP];
  __shared__ int scanbuf[256];
  const int tid = threadIdx.x;
  const int ebase = blockIdx.x * CAP;
  const int n_e = min(CAP, E_TOT - ebase);

  for (int j = tid; j < NBKT_PAD; j += 256) hist[j] = 0;
  __syncthreads();

#pragma unroll
  for (int i = 0; i < 16; ++i) {
    int e = ebase + i * 256 + tid;
    if (e < ebase + n_e) {
      int r = 0;
#pragma unroll
      for (int k = 1; k < 6; ++k) r += (e >= EB[k]);
      int local = e - EB[r];
      int dst = ep.p[r][EC[r] + local];
      int bk = BKB[r] + (dst >> SH[r]);
      atomicAdd(&hist[bk], 1);
    }
  }
  __syncthreads();

  int own = 0;
  {
    int j0 = tid * 5;
#pragma unroll
    for (int j = 0; j < 5; ++j) own += hist[j0 + j];
    scanbuf[tid] = own;
  }
  __syncthreads();
  for (int o = 1; o < 256; o <<= 1) {
    int v = (tid >= o) ? scanbuf[tid - o] : 0;
    __syncthreads();
    scanbuf[tid] += v;
    __syncthreads();
  }
  {
    int run = scanbuf[tid] - own;
    int j0 = tid * 5;
#pragma unroll
    for (int j = 0; j < 5; ++j) {
      int c = hist[j0 + j];
      off[j0 + j] = run;
      cur[j0 + j] = run;
      hist[j0 + j] = (c > 0) ? atomicAdd(&gcursor[j0 + j], c) : 0;
      run += c;
    }
  }
  __syncthreads();

#pragma unroll
  for (int i = 0; i < 16; ++i) {
    int e = ebase + i * 256 + tid;
    if (e < ebase + n_e) {
      int r = 0;
#pragma unroll
      for (int k = 1; k < 6; ++k) r += (e >= EB[k]);
      int local = e - EB[r];
      int src = ep.p[r][local];
      int dst = ep.p[r][EC[r] + local];
      int bk = BKB[r] + (dst >> SH[r]);
      int dl = dst & ((1 << SH[r]) - 1);
      u32 val = ((u32)dl << 18) | (u32)src;
      int l = atomicAdd(&cur[bk], 1);
      vals[l] = val;
      bks[l] = (u16)bk;
    }
  }
  __syncthreads();

  for (int idx = tid; idx < n_e; idx += 256) {
    int bk = bks[idx];
    int g = hist[bk] + (idx - off[bk]);
    colbuf2[g] = vals[idx];
  }
}

__global__ __launch_bounds__(256) void bucket2_kernel(const int* __restrict__ bktbase,
                                                      const u32* __restrict__ colbuf2,
                                                      int* __restrict__ colbuf,
                                                      int* __restrict__ row_ptr,
                                                      float* __restrict__ inv) {
  REL_TABLES
  __shared__ u32 vals[CAP];
  __shared__ int outb[CAP];
  __shared__ int rcnt[512];
  __shared__ int roff[512];
  __shared__ int scanbuf[256];
  const int tid = threadIdx.x;
  const int bk = blockIdx.x;
  int r = 0;
#pragma unroll
  for (int i = 1; i < 6; ++i) r += (bk >= BKB[i]);
  int bkloc = bk - BKB[r];
  int r0 = GB[r] + (bkloc << SH[r]);
  int nrows = min(1 << SH[r], ND[r] - (bkloc << SH[r]));
  int p0 = bktbase[bk];
  int p1 = bktbase[bk + 1];
  int n = p1 - p0;
  bool fits = (n <= CAP);

  for (int dl = tid; dl < nrows; dl += 256) rcnt[dl] = 0;
  __syncthreads();
  if (fits) {
    for (int i = tid; i < n; i += 256) {
      u32 v = colbuf2[p0 + i];
      vals[i] = v;
      atomicAdd(&rcnt[v >> 18], 1);
    }
  } else {
    for (int i = tid; i < n; i += 256) {
      u32 v = colbuf2[p0 + i];
      atomicAdd(&rcnt[v >> 18], 1);
    }
  }
  __syncthreads();

  int d0 = tid * 2, d1 = tid * 2 + 1;
  int c0 = (d0 < nrows) ? rcnt[d0] : 0;
  int c1 = (d1 < nrows) ? rcnt[d1] : 0;
  int own = c0 + c1;
  scanbuf[tid] = own;
  __syncthreads();
  for (int o = 1; o < 256; o <<= 1) {
    int v = (tid >= o) ? scanbuf[tid - o] : 0;
    __syncthreads();
    scanbuf[tid] += v;
    __syncthreads();
  }
  int run = scanbuf[tid] - own;
  if (d0 < nrows) {
    roff[d0] = run;
    row_ptr[r0 + d0] = p0 + run;
    inv[r0 + d0] = 1.0f / (float)(c0 > 1 ? c0 : 1);
  }
  if (d1 < nrows) {
    roff[d1] = run + c0;
    row_ptr[r0 + d1] = p0 + run + c0;
    inv[r0 + d1] = 1.0f / (float)(c1 > 1 ? c1 : 1);
  }
  __syncthreads();

  if (fits) {
    for (int i = tid; i < n; i += 256) {
      u32 v = vals[i];
      int dl = v >> 18;
      int pos = atomicAdd(&roff[dl], 1);
      outb[pos] = (int)(v & 0x3FFFFu);
    }
    __syncthreads();
    for (int i = tid; i < n; i += 256) colbuf[p0 + i] = outb[i];
  } else {
    for (int i = tid; i < n; i += 256) {
      u32 v = colbuf2[p0 + i];
      int dl = v >> 18;
      int pos = atomicAdd(&roff[dl], 1);
      colbuf[p0 + pos] = (int)(v & 0x3FFFFu);
    }
  }
}

// ---------------- degree-sort (65 classes, descending) ----------------
__global__ __launch_bounds__(256) void dhist_kernel(const int* __restrict__ row_ptr,
                                                    int* __restrict__ clscnt) {
  __shared__ int h[65];
  int tid = threadIdx.x;
  if (tid < 65) h[tid] = 0;
  __syncthreads();
  int base = blockIdx.x * 1024 + tid * 4;
#pragma unroll
  for (int i = 0; i < 4; ++i) {
    int g = base + i;
    if (g < G_TOT) {
      int d = row_ptr[g + 1] - row_ptr[g];
      int c = 64 - (d < 64 ? d : 64);
      atomicAdd(&h[c], 1);
    }
  }
  __syncthreads();
  if (tid < 65 && h[tid]) atomicAdd(&clscnt[tid], h[tid]);
}

__global__ void dscan_kernel(const int* __restrict__ clscnt, int* __restrict__ clscur) {
  if (threadIdx.x == 0) {
    int run = 0;
    for (int c = 0; c < 65; ++c) {
      clscur[c] = run;
      run += clscnt[c];
    }
  }
}

__global__ __launch_bounds__(256) void dscatter_kernel(const int* __restrict__ row_ptr,
                                                       const float* __restrict__ inv,
                                                       int* __restrict__ clscur,
                                                       uint4* __restrict__ descs) {
  constexpr int GBp[7] = {0, 50000, 150000, 250000, 300000, 301000, 351000};
  __shared__ int h[65], bas[65], cur[65];
  int tid = threadIdx.x;
  if (tid < 65) h[tid] = 0;
  __syncthreads();
  int base = blockIdx.x * 1024 + tid * 4;
  int cls[4];
#pragma unroll
  for (int i = 0; i < 4; ++i) {
    int g = base + i;
    cls[i] = -1;
    if (g < G_TOT) {
      int d = row_ptr[g + 1] - row_ptr[g];
      int c = 64 - (d < 64 ? d : 64);
      cls[i] = c;
      atomicAdd(&h[c], 1);
    }
  }
  __syncthreads();
  if (tid < 65) {
    bas[tid] = h[tid] ? atomicAdd(&clscur[tid], h[tid]) : 0;
    cur[tid] = 0;
  }
  __syncthreads();
#pragma unroll
  for (int i = 0; i < 4; ++i) {
    int g = base + i;
    if (g < G_TOT) {
      int c = cls[i];
      int p = bas[c] + atomicAdd(&cur[c], 1);
      int s = row_ptr[g];
      int cnt = row_ptr[g + 1] - s;
      int r = 0;
#pragma unroll
      for (int k = 1; k < 6; ++k) r += (g >= GBp[k]);
      uint4 d;
      d.x = (u32)s;
      d.y = (u32)cnt | ((u32)r << 24);
      d.z = (u32)(g - GBp[r]);
      d.w = __float_as_uint(inv[g]);
      descs[p] = d;
    }
  }
}

// ---------------- merged prep: 3 casts + 6 weight preps, one launch -------
struct PrepArgs {
  const float* xu; const float* xb; const float* xc;
  const float* W1l; const float* W1r; const float* b1;
  const float* W2l; const float* W2r; const float* b2;
  u16* A1u; u16* A1b; u16* A1c;
  u16* B1u; u16* B1b; u16* B1c;
  u16* B2u; u16* B2b; u16* B2c;
  float* biasbuf;
};

__device__ __forceinline__ void do_cast(const float* __restrict__ x, u16* __restrict__ aself,
                                        int K, int N, int t) {
  if (t >= N * 32) return;
  int row = t >> 5, q = t & 31;
  float4 v = ((const float4*)(x + (size_t)row * 128))[q];
  ushort4 o;
  o.x = f2bf(v.x); o.y = f2bf(v.y); o.z = f2bf(v.z); o.w = f2bf(v.w);
  ((ushort4*)(aself + (size_t)row * K))[q] = o;
}

__device__ __forceinline__ void do_wprep(const float* __restrict__ Wl, const float* __restrict__ Wr,
                                         const float* __restrict__ bsrc, int rx, int ry, int rz,
                                         int nrel, int K, u16* __restrict__ Bcat,
                                         float* __restrict__ bias, int t) {
  int total = 128 * K;
  if (t < total) {
    int o = t / K, k = t - o * K;
    int j = k >> 7, d = k & 127;
    float val;
    if (j < nrel) {
      int rel = (j == 0) ? rx : ((j == 1) ? ry : rz);
      val = Wl[rel * 16384 + o * 128 + d];
    } else {
      val = 0.f;
      if (nrel > 0) val += Wr[rx * 16384 + o * 128 + d];
      if (nrel > 1) val += Wr[ry * 16384 + o * 128 + d];
      if (nrel > 2) val += Wr[rz * 16384 + o * 128 + d];
    }
    Bcat[t] = f2bf(val);
  }
  if (t < 128) {
    float s = 0.f;
    if (nrel > 0) s += bsrc[rx * 128 + t];
    if (nrel > 1) s += bsrc[ry * 128 + t];
    if (nrel > 2) s += bsrc[rz * 128 + t];
    bias[t] = s;
  }
}

// block ranges
#define PB_CU 0
#define PB_CB 12500
#define PB_CC 18750
#define PB_W1U 18875
#define PB_W1B 19067
#define PB_W1C 19323
#define PB_W2U 19451
#define PB_W2B 19643
#define PB_W2C 19899
#define PB_END 20027

__global__ __launch_bounds__(256) void prep_kernel(PrepArgs a) {
  int b = blockIdx.x;
  int tid = threadIdx.x;
  if (b < PB_CB) {
    do_cast(a.xu, a.A1u + SELF_U, KU, NU, (b - PB_CU) * 256 + tid);
  } else if (b < PB_CC) {
    do_cast(a.xb, a.A1b + SELF_B, KB, NB, (b - PB_CB) * 256 + tid);
  } else if (b < PB_W1U) {
    do_cast(a.xc, a.A1c + SELF_C, KC, NC, (b - PB_CC) * 256 + tid);
  } else if (b < PB_W1B) {
    do_wprep(a.W1l, a.W1r, a.b1, 1, 2, 0, 2, KU, a.B1u, a.biasbuf + 0 * 128, (b - PB_W1U) * 256 + tid);
  } else if (b < PB_W1C) {
    do_wprep(a.W1l, a.W1r, a.b1, 0, 3, 5, 3, KB, a.B1b, a.biasbuf + 1 * 128, (b - PB_W1B) * 256 + tid);
  } else if (b < PB_W2U) {
    do_wprep(a.W1l, a.W1r, a.b1, 4, 4, 4, 1, KC, a.B1c, a.biasbuf + 2 * 128, (b - PB_W1C) * 256 + tid);
  } else if (b < PB_W2B) {
    do_wprep(a.W2l, a.W2r, a.b2, 1, 2, 0, 2, KU, a.B2u, a.biasbuf + 3 * 128, (b - PB_W2U) * 256 + tid);
  } else if (b < PB_W2C) {
    do_wprep(a.W2l, a.W2r, a.b2, 0, 3, 5, 3, KB, a.B2b, a.biasbuf + 4 * 128, (b - PB_W2B) * 256 + tid);
  } else {
    do_wprep(a.W2l, a.W2r, a.b2, 4, 4, 4, 1, KC, a.B2c, a.biasbuf + 5 * 128, (b - PB_W2C) * 256 + tid);
  }
}

// ---------------- pull aggregation (unchanged) ----------------
__global__ __launch_bounds__(256) void pull_kernel(const int* __restrict__ colbuf,
                                                   const uint4* __restrict__ descs,
                                                   PullMeta pm) {
  const int l16 = threadIdx.x & 15;
  const int gbase = (threadIdx.x & 63) & ~15;

  for (int idx = blockIdx.x * 16 + (threadIdx.x >> 4); idx < G_TOT; idx += PULL_GRID * 16) {
    uint4 d = descs[idx];
    int s = (int)d.x;
    int cntAll = (int)(d.y & 0xFFFFFFu);
    int r = (int)(d.y >> 24);
    int dstIdx = (int)d.z;
    float sc = __uint_as_float(d.w);
    int e = s + cntAll;
    const uint4* sb = (const uint4*)pm.src[r];
    const int skv = pm.srcK[r] >> 3;

    float a0 = 0.f, a1 = 0.f, a2 = 0.f, a3 = 0.f, a4 = 0.f, a5 = 0.f, a6 = 0.f, a7 = 0.f;
#define ACC8(v)                                      \
    a0 += bf_lo((v).x); a1 += bf_hi((v).x);          \
    a2 += bf_lo((v).y); a3 += bf_hi((v).y);          \
    a4 += bf_lo((v).z); a5 += bf_hi((v).z);          \
    a6 += bf_lo((v).w); a7 += bf_hi((v).w);

    for (int c0 = s; c0 < e; c0 += 16) {
      int cnt = e - c0;
      if (cnt > 16) cnt = 16;
      int myIdx = (l16 < cnt) ? colbuf[c0 + l16] : 0;
      int j = 0;
      for (; j + 8 <= cnt; j += 8) {
        uint4 v[8];
#pragma unroll
        for (int q = 0; q < 8; ++q) {
          int i0 = __shfl(myIdx, gbase + j + q);
          v[q] = sb[(size_t)i0 * skv + l16];
        }
#pragma unroll
        for (int q = 0; q < 8; ++q) { ACC8(v[q]) }
      }
      if (j + 4 <= cnt) {
        uint4 v[4];
#pragma unroll
        for (int q = 0; q < 4; ++q) {
          int i0 = __shfl(myIdx, gbase + j + q);
          v[q] = sb[(size_t)i0 * skv + l16];
        }
#pragma unroll
        for (int q = 0; q < 4; ++q) { ACC8(v[q]) }
        j += 4;
      }
      if (j + 2 <= cnt) {
        uint4 v[2];
#pragma unroll
        for (int q = 0; q < 2; ++q) {
          int i0 = __shfl(myIdx, gbase + j + q);
          v[q] = sb[(size_t)i0 * skv + l16];
        }
#pragma unroll
        for (int q = 0; q < 2; ++q) { ACC8(v[q]) }
        j += 2;
      }
      if (j < cnt) {
        int i0 = __shfl(myIdx, gbase + j);
        uint4 v0 = sb[(size_t)i0 * skv + l16];
        ACC8(v0)
      }
    }
#undef ACC8
    uint4 o;
    o.x = (u32)f2bf(a0 * sc) | ((u32)f2bf(a1 * sc) << 16);
    o.y = (u32)f2bf(a2 * sc) | ((u32)f2bf(a3 * sc) << 16);
    o.z = (u32)f2bf(a4 * sc) | ((u32)f2bf(a5 * sc) << 16);
    o.w = (u32)f2bf(a6 * sc) | ((u32)f2bf(a7 * sc) << 16);
    ((uint4*)(pm.dst[r] + (size_t)dstIdx * pm.dstK[r]))[l16] = o;
  }
}

// ---------------- merged bf16 MFMA GEMM ----------------
// 256x128 tile / block, 4 waves (each 64 rows x 128 cols = 4x8 frags, 32 MFMA/step),
// 3-stage counted-vmcnt pipeline, LDS 3 x (16KB A + 8KB B) = 72KB -> 2 blocks/CU.
typedef __attribute__((ext_vector_type(8))) short bf16x8;
typedef __attribute__((ext_vector_type(4))) float f32x4;

#define GLOAD16(g, l)                                                              \
  __builtin_amdgcn_global_load_lds((const __attribute__((address_space(1))) void*)(g), \
                                   (__attribute__((address_space(3))) void*)(l), 16, 0, 0)

#define TM 256
#define STG 24576  // per-stage LDS: A 16KB + B 8KB

struct G3 {
  const u16* A[3];
  const u16* B[3];
  const float* bias[3];
  int M[3];
  int K[3];
  u16* outBf[3];
  int outStride[3];
  int outOff[3];
  float* outF;
  long long outBase[3];
  int outF32;
  int blkStart1;
  int blkStart2;
};

// bank-swizzle: rows 0..7 cover all 32 banks at a fixed 16B slot (2-way alias r/r+8 is free)
__device__ __forceinline__ int swz(int row) {
  return (((row & 3) ^ ((row >> 2) & 1)) << 4);
}

// stage NCH*16 rows x 32 cols bf16 into ldsBase. Linear LDS dest + inverse-swizzled
// global source (XOR involution, both-sides-or-neither rule).
template <int NCH>
__device__ __forceinline__ void stageT(const u16* __restrict__ M, long long rowBase,
                                       int K, int k0, char* ldsBase, int w, int lane) {
#pragma unroll
  for (int i = 0; i < NCH; ++i) {
    int c = w + i * 4;
    int row = c * 16 + (lane >> 2);
    int scol = ((lane & 3) * 16) ^ swz(row);
    const char* g = (const char*)M + ((rowBase + row) * (long long)K + k0) * 2 + scol;
    GLOAD16(g, ldsBase + c * 1024 + lane * 16);
  }
}

__global__ __launch_bounds__(256, 2) void gemm3_kernel(G3 a) {
  __shared__ char lds[3 * STG];  // 72 KB
  const int tid = threadIdx.x;
  const int lane = tid & 63;
  const int w = tid >> 6;
  int b = blockIdx.x;
  int j = (b >= a.blkStart2) ? 2 : ((b >= a.blkStart1) ? 1 : 0);
  int bloc = b - (j == 2 ? a.blkStart2 : (j == 1 ? a.blkStart1 : 0));
  const long long rowBase = (long long)bloc * TM;
  const u16* A = a.A[j];
  const u16* B = a.B[j];
  const int K = a.K[j];
  const int M = a.M[j];
  const int nk = K >> 5;  // K/32 steps: 12 / 16 / 8

  f32x4 acc[4][8];
#pragma unroll
  for (int m = 0; m < 4; ++m)
#pragma unroll
    for (int n = 0; n < 8; ++n) acc[m][n] = (f32x4){0.f, 0.f, 0.f, 0.f};

  // prologue: prefetch stages 0,1 (6 loads/wave each: 4 A-chunks + 2 B-chunks)
  stageT<4>(A, rowBase, K, 0, lds + 0 * STG, w, lane);
  stageT<2>(B, 0, K, 0, lds + 0 * STG + 16384, w, lane);
  if (nk > 1) {
    stageT<4>(A, rowBase, K, 32, lds + 1 * STG, w, lane);
    stageT<2>(B, 0, K, 32, lds + 1 * STG + 16384, w, lane);
  }

  const int cb = (lane >> 4) * 16;
  const int rA0 = w * 64 + (lane & 15);
  const int rB0 = lane & 15;

  for (int k = 0; k < nk; ++k) {
    // issue stage k+2 (into buffer freed at end of step k-1)
    if (k + 2 < nk) {
      int sb2 = ((k + 2) % 3) * STG;
      stageT<4>(A, rowBase, K, (k + 2) * 32, lds + sb2, w, lane);
      stageT<2>(B, 0, K, (k + 2) * 32, lds + sb2 + 16384, w, lane);
      asm volatile("s_waitcnt vmcnt(12)" ::: "memory");  // stage k landed; k+1,k+2 in flight
    } else if (k + 1 < nk) {
      asm volatile("s_waitcnt vmcnt(6)" ::: "memory");   // stage k landed; k+1 in flight
    } else {
      asm volatile("s_waitcnt vmcnt(0)" ::: "memory");   // last stage
    }
    __builtin_amdgcn_s_barrier();  // all waves' stage-k loads are in LDS
    asm volatile("" ::: "memory");

    const char* SA = lds + (k % 3) * STG;
    const char* SB = SA + 16384;
    bf16x8 af[4], bfr[8];
#pragma unroll
    for (int m = 0; m < 4; ++m) {
      int rr = rA0 + m * 16;
      af[m] = *(const bf16x8*)(SA + rr * 64 + (cb ^ swz(rr)));
    }
#pragma unroll
    for (int n = 0; n < 8; ++n) {
      int rr = rB0 + n * 16;
      bfr[n] = *(const bf16x8*)(SB + rr * 64 + (cb ^ swz(rr)));
    }
    __builtin_amdgcn_s_setprio(1);
#pragma unroll
    for (int m = 0; m < 4; ++m)
#pragma unroll
      for (int n = 0; n < 8; ++n)
        acc[m][n] = __builtin_amdgcn_mfma_f32_16x16x32_bf16(af[m], bfr[n], acc[m][n], 0, 0, 0);
    __builtin_amdgcn_s_setprio(0);

    asm volatile("" ::: "memory");
    __builtin_amdgcn_s_barrier();  // buf k fully read before stage k+3 overwrites it
    asm volatile("" ::: "memory");
  }

  const float* bias = a.bias[j];
  const int colBase = lane & 15;
#pragma unroll
  for (int m = 0; m < 4; ++m) {
    long long r0 = rowBase + w * 64 + m * 16 + ((lane >> 4) * 4);
#pragma unroll
    for (int n = 0; n < 8; ++n) {
      int col = n * 16 + colBase;
      float bv = bias[col];
#pragma unroll
      for (int q = 0; q < 4; ++q) {
        long long row = r0 + q;
        if (row < M) {
          float v = acc[m][n][q] + bv;
          v = v > 0.f ? v : 0.f;
          if (a.outF32)
            a.outF[a.outBase[j] + row * 128 + col] = v;
          else
            a.outBf[j][row * (long long)a.outStride[j] + a.outOff[j] + col] = f2bf(v);
        }
      }
    }
  }
}

// ---------------- host launcher ----------------
extern "C" void kernel_launch(void* const* d_in, const int* in_sizes, int n_in,
                              void* d_out, int out_size, void* d_ws, size_t ws_size,
                              hipStream_t stream) {
  const float* xu = (const float*)d_in[0];
  const float* xb = (const float*)d_in[1];
  const float* xc = (const float*)d_in[2];
  const float* W1l = (const float*)d_in[3];
  const float* b1 = (const float*)d_in[4];
  const float* W1r = (const float*)d_in[5];
  const float* W2l = (const float*)d_in[6];
  const float* b2 = (const float*)d_in[7];
  const float* W2r = (const float*)d_in[8];
  EdgePtrs ep;
  ep.p[0] = (const int*)d_in[9];
  ep.p[1] = (const int*)d_in[10];
  ep.p[2] = (const int*)d_in[11];
  ep.p[3] = (const int*)d_in[12];
  ep.p[4] = (const int*)d_in[13];
  ep.p[5] = (const int*)d_in[14];
  float* out = (float*)d_out;

  char* ws = (char*)d_ws;
  size_t off = 0;
  auto alloc = [&](size_t b) {
    char* p = ws + off;
    off = (off + b + 255) & ~(size_t)255;
    return p;
  };

  int* row_ptr = (int*)alloc((size_t)(G_TOT + 1) * 4);
  float* inv = (float*)alloc((size_t)G_TOT * 4);
  int* colbuf = (int*)alloc((size_t)E_TOT * 4);
  u32* colbuf2 = (u32*)alloc((size_t)E_TOT * 4);
  int* gcursor = (int*)alloc((size_t)NBKT * 4);
  int* bktcnt = (int*)alloc((size_t)NBKT * 4);
  int* bktbase = (int*)alloc((size_t)(NBKT + 1) * 4);
  uint4* descs = (uint4*)alloc((size_t)G_TOT * 16);
  int* clsbuf = (int*)alloc(130 * 4);
  u16* A1u = (u16*)alloc((size_t)MU_PAD * KU * 2);
  u16* A1b = (u16*)alloc((size_t)MB_PAD * KB * 2);
  u16* A1c = (u16*)alloc((size_t)MC_PAD * KC * 2);
  u16* A2u = (u16*)alloc((size_t)MU_PAD * KU * 2);
  u16* A2b = (u16*)alloc((size_t)MB_PAD * KB * 2);
  u16* A2c = (u16*)alloc((size_t)MC_PAD * KC * 2);
  u16* B1u = (u16*)alloc((size_t)128 * KU * 2);
  u16* B1b = (u16*)alloc((size_t)128 * KB * 2);
  u16* B1c = (u16*)alloc((size_t)128 * KC * 2);
  u16* B2u = (u16*)alloc((size_t)128 * KU * 2);
  u16* B2b = (u16*)alloc((size_t)128 * KB * 2);
  u16* B2c = (u16*)alloc((size_t)128 * KC * 2);
  float* biasbuf = (float*)alloc(6 * 128 * 4);

  // CSR build
  hipMemsetAsync(bktcnt, 0, (size_t)NBKT * 4, stream);
  hipMemsetAsync(clsbuf, 0, 130 * 4, stream);
  bhist_kernel<<<(E_TOT + 16383) / 16384, 256, 0, stream>>>(ep, bktcnt);
  bscan_kernel<<<1, 256, 0, stream>>>(bktcnt, bktbase, gcursor, row_ptr);
  bucket1_kernel<<<(E_TOT + CAP - 1) / CAP, 256, 0, stream>>>(ep, gcursor, colbuf2);
  bucket2_kernel<<<NBKT, 256, 0, stream>>>(bktbase, colbuf2, colbuf, row_ptr, inv);

  // degree sort -> sequential descriptors
  int nblk = (G_TOT + 1023) / 1024;
  dhist_kernel<<<nblk, 256, 0, stream>>>(row_ptr, clsbuf);
  dscan_kernel<<<1, 64, 0, stream>>>(clsbuf, clsbuf + 65);
  dscatter_kernel<<<nblk, 256, 0, stream>>>(row_ptr, inv, clsbuf + 65, descs);

  // merged prep (casts + weight concats)
  PrepArgs pa;
  pa.xu = xu; pa.xb = xb; pa.xc = xc;
  pa.W1l = W1l; pa.W1r = W1r; pa.b1 = b1;
  pa.W2l = W2l; pa.W2r = W2r; pa.b2 = b2;
  pa.A1u = A1u; pa.A1b = A1b; pa.A1c = A1c;
  pa.B1u = B1u; pa.B1b = B1b; pa.B1c = B1c;
  pa.B2u = B2u; pa.B2b = B2b; pa.B2c = B2c;
  pa.biasbuf = biasbuf;
  prep_kernel<<<PB_END, 256, 0, stream>>>(pa);

  // ---- layer 1 ----
  PullMeta pm1;
  pm1.src[0] = A1u + SELF_U; pm1.srcK[0] = KU; pm1.dst[0] = A1b + 0;   pm1.dstK[0] = KB;
  pm1.src[1] = A1b + SELF_B; pm1.srcK[1] = KB; pm1.dst[1] = A1u + 0;   pm1.dstK[1] = KU;
  pm1.src[2] = A1u + SELF_U; pm1.srcK[2] = KU; pm1.dst[2] = A1u + 128; pm1.dstK[2] = KU;
  pm1.src[3] = A1b + SELF_B; pm1.srcK[3] = KB; pm1.dst[3] = A1b + 128; pm1.dstK[3] = KB;
  pm1.src[4] = A1b + SELF_B; pm1.srcK[4] = KB; pm1.dst[4] = A1c + 0;   pm1.dstK[4] = KC;
  pm1.src[5] = A1c + SELF_C; pm1.srcK[5] = KC; pm1.dst[5] = A1b + 256; pm1.dstK[5] = KB;
  pull_kernel<<<PULL_GRID, 256, 0, stream>>>(colbuf, descs, pm1);

  G3 g1;
  g1.A[0] = A1u; g1.A[1] = A1b; g1.A[2] = A1c;
  g1.B[0] = B1u; g1.B[1] = B1b; g1.B[2] = B1c;
  g1.bias[0] = biasbuf + 0 * 128; g1.bias[1] = biasbuf + 1 * 128; g1.bias[2] = biasbuf + 2 * 128;
  g1.M[0] = NU; g1.M[1] = NB; g1.M[2] = NC;
  g1.K[0] = KU; g1.K[1] = KB; g1.K[2] = KC;
  g1.outBf[0] = A2u; g1.outBf[1] = A2b; g1.outBf[2] = A2c;
  g1.outStride[0] = KU; g1.outStride[1] = KB; g1.outStride[2] = KC;
  g1.outOff[0] = SELF_U; g1.outOff[1] = SELF_B; g1.outOff[2] = SELF_C;
  g1.outF = nullptr;
  g1.outBase[0] = g1.outBase[1] = g1.outBase[2] = 0;
  g1.outF32 = 0;
  g1.blkStart1 = MU_PAD / TM;
  g1.blkStart2 = MU_PAD / TM + MB_PAD / TM;
  gemm3_kernel<<<MU_PAD / TM + MB_PAD / TM + MC_PAD / TM, 256, 0, stream>>>(g1);

  // ---- layer 2 ----
  PullMeta pm2;
  pm2.src[0] = A2u + SELF_U; pm2.srcK[0] = KU; pm2.dst[0] = A2b + 0;   pm2.dstK[0] = KB;
  pm2.src[1] = A2b + SELF_B; pm2.srcK[1] = KB; pm2.dst[1] = A2u + 0;   pm2.dstK[1] = KU;
  pm2.src[2] = A2u + SELF_U; pm2.srcK[2] = KU; pm2.dst[2] = A2u + 128; pm2.dstK[2] = KU;
  pm2.src[3] = A2b + SELF_B; pm2.srcK[3] = KB; pm2.dst[3] = A2b + 128; pm2.dstK[3] = KB;
  pm2.src[4] = A2b + SELF_B; pm2.srcK[4] = KB; pm2.dst[4] = A2c + 0;   pm2.dstK[4] = KC;
  pm2.src[5] = A2c + SELF_C; pm2.srcK[5] = KC; pm2.dst[5] = A2b + 256; pm2.dstK[5] = KB;
  pull_kernel<<<PULL_GRID, 256, 0, stream>>>(colbuf, descs, pm2);

  G3 g2;
  g2.A[0] = A2u; g2.A[1] = A2b; g2.A[2] = A2c;
  g2.B[0] = B2u; g2.B[1] = B2b; g2.B[2] = B2c;
  g2.bias[0] = biasbuf + 3 * 128; g2.bias[1] = biasbuf + 4 * 128; g2.bias[2] = biasbuf + 5 * 128;
  g2.M[0] = NU; g2.M[1] = NB; g2.M[2] = NC;
  g2.K[0] = KU; g2.K[1] = KB; g2.K[2] = KC;
  g2.outBf[0] = g2.outBf[1] = g2.outBf[2] = nullptr;
  g2.outStride[0] = g2.outStride[1] = g2.outStride[2] = 0;
  g2.outOff[0] = g2.outOff[1] = g2.outOff[2] = 0;
  g2.outF = out;
  g2.outBase[0] = 0;
  g2.outBase[1] = (long long)NU * 128;
  g2.outBase[2] = (long long)(NU + NB) * 128;
  g2.outF32 = 1;
  g2.blkStart1 = MU_PAD / TM;
  g2.blkStart2 = MU_PAD / TM + MB_PAD / TM;
  gemm3_kernel<<<MU_PAD / TM + MB_PAD / TM + MC_PAD / TM, 256, 0, stream>>>(g2);
}

// Round 2
// 428.540 us; speedup vs baseline: 1.1350x; 1.1350x over previous
//
#include <hip/hip_runtime.h>
#include <stdint.h>

typedef unsigned int u32;
typedef unsigned short u16;

// ---------------- problem constants ----------------
#define NU 100000
#define NB 50000
#define NC 1000

#define E_TOT 2000000
#define G_TOT 351000

#define KU 384
#define KB 512
#define KC 256
#define SELF_U 256
#define SELF_B 384
#define SELF_C 128
#define MU_PAD 100096
#define MB_PAD 50176
#define MC_PAD 1024

#define CAP 4096
#define NBKT 1034
#define NBKT_PAD 1280

#define PULL_GRID 2048

// ---------------- helpers ----------------
__device__ __forceinline__ u16 f2bf(float f) {
  u32 u = __float_as_uint(f);
  u += 0x7fffu + ((u >> 16) & 1u);
  return (u16)(u >> 16);
}
__device__ __forceinline__ float bf_lo(u32 v) { return __uint_as_float(v << 16); }
__device__ __forceinline__ float bf_hi(u32 v) { return __uint_as_float(v & 0xffff0000u); }

struct EdgePtrs { const int* p[6]; };
struct PullMeta {
  const u16* src[6];
  u16* dst[6];
  int srcK[6];
  int dstK[6];
};

#define REL_TABLES                                                              \
  constexpr int EB[7] = {0, 500000, 1000000, 1300000, 1600000, 1800000, 2000000}; \
  constexpr int EC[6] = {500000, 500000, 300000, 300000, 200000, 200000};         \
  constexpr int GB[6] = {0, 50000, 150000, 250000, 300000, 301000};               \
  constexpr int SH[6] = {8, 9, 9, 9, 2, 9};                                       \
  constexpr int BKB[7] = {0, 196, 392, 588, 686, 936, 1034};                      \
  constexpr int ND[6] = {50000, 100000, 100000, 50000, 1000, 50000};

// ---------------- CSR build ----------------
__global__ __launch_bounds__(256) void bhist_kernel(EdgePtrs ep, int* __restrict__ bktcnt) {
  REL_TABLES
  __shared__ int h[NBKT];
  const int tid = threadIdx.x;
  for (int j = tid; j < NBKT; j += 256) h[j] = 0;
  __syncthreads();
  const int ebase = blockIdx.x * 16384;
  const int eend = min(ebase + 16384, E_TOT);
  for (int e = ebase + tid; e < eend; e += 256) {
    int r = 0;
#pragma unroll
    for (int i = 1; i < 6; ++i) r += (e >= EB[i]);
    int dst = ep.p[r][EC[r] + e - EB[r]];
    atomicAdd(&h[BKB[r] + (dst >> SH[r])], 1);
  }
  __syncthreads();
  for (int j = tid; j < NBKT; j += 256)
    if (h[j]) atomicAdd(&bktcnt[j], h[j]);
}

__global__ __launch_bounds__(256) void bscan_kernel(const int* __restrict__ bktcnt,
                                                    int* __restrict__ bktbase,
                                                    int* __restrict__ gcursor,
                                                    int* __restrict__ row_ptr) {
  __shared__ int scanbuf[256];
  int tid = threadIdx.x;
  int c[5];
  int own = 0;
  int j0 = tid * 5;
#pragma unroll
  for (int j = 0; j < 5; ++j) {
    int b = j0 + j;
    c[j] = (b < NBKT) ? bktcnt[b] : 0;
    own += c[j];
  }
  scanbuf[tid] = own;
  __syncthreads();
  for (int o = 1; o < 256; o <<= 1) {
    int v = (tid >= o) ? scanbuf[tid - o] : 0;
    __syncthreads();
    scanbuf[tid] += v;
    __syncthreads();
  }
  int run = scanbuf[tid] - own;
#pragma unroll
  for (int j = 0; j < 5; ++j) {
    int b = j0 + j;
    if (b < NBKT) {
      bktbase[b] = run;
      gcursor[b] = run;
      run += c[j];
    }
  }
  if (tid == 255) {
    bktbase[NBKT] = E_TOT;
    row_ptr[G_TOT] = E_TOT;
  }
}

__global__ __launch_bounds__(256) void bucket1_kernel(EdgePtrs ep, int* __restrict__ gcursor,
                                                      u32* __restrict__ colbuf2) {
  REL_TABLES
  __shared__ int hist[NBKT_PAD];
  __shared__ int off[NBKT_PAD];
  __shared__ int cur[NBKT_PAD];
  __shared__ u32 vals[CAP];
  __shared__ u16 bks[CAP];
  __shared__ int scanbuf[256];
  const int tid = threadIdx.x;
  const int ebase = blockIdx.x * CAP;
  const int n_e = min(CAP, E_TOT - ebase);

  for (int j = tid; j < NBKT_PAD; j += 256) hist[j] = 0;
  __syncthreads();

#pragma unroll
  for (int i = 0; i < 16; ++i) {
    int e = ebase + i * 256 + tid;
    if (e < ebase + n_e) {
      int r = 0;
#pragma unroll
      for (int k = 1; k < 6; ++k) r += (e >= EB[k]);
      int local = e - EB[r];
      int dst = ep.p[r][EC[r] + local];
      int bk = BKB[r] + (dst >> SH[r]);
      atomicAdd(&hist[bk], 1);
    }
  }
  __syncthreads();

  int own = 0;
  {
    int j0 = tid * 5;
#pragma unroll
    for (int j = 0; j < 5; ++j) own += hist[j0 + j];
    scanbuf[tid] = own;
  }
  __syncthreads();
  for (int o = 1; o < 256; o <<= 1) {
    int v = (tid >= o) ? scanbuf[tid - o] : 0;
    __syncthreads();
    scanbuf[tid] += v;
    __syncthreads();
  }
  {
    int run = scanbuf[tid] - own;
    int j0 = tid * 5;
#pragma unroll
    for (int j = 0; j < 5; ++j) {
      int c = hist[j0 + j];
      off[j0 + j] = run;
      cur[j0 + j] = run;
      hist[j0 + j] = (c > 0) ? atomicAdd(&gcursor[j0 + j], c) : 0;
      run += c;
    }
  }
  __syncthreads();

#pragma unroll
  for (int i = 0; i < 16; ++i) {
    int e = ebase + i * 256 + tid;
    if (e < ebase + n_e) {
      int r = 0;
#pragma unroll
      for (int k = 1; k < 6; ++k) r += (e >= EB[k]);
      int local = e - EB[r];
      int src = ep.p[r][local];
      int dst = ep.p[r][EC[r] + local];
      int bk = BKB[r] + (dst >> SH[r]);
      int dl = dst & ((1 << SH[r]) - 1);
      u32 val = ((u32)dl << 18) | (u32)src;
      int l = atomicAdd(&cur[bk], 1);
      vals[l] = val;
      bks[l] = (u16)bk;
    }
  }
  __syncthreads();

  for (int idx = tid; idx < n_e; idx += 256) {
    int bk = bks[idx];
    int g = hist[bk] + (idx - off[bk]);
    colbuf2[g] = vals[idx];
  }
}

__global__ __launch_bounds__(256) void bucket2_kernel(const int* __restrict__ bktbase,
                                                      const u32* __restrict__ colbuf2,
                                                      int* __restrict__ colbuf,
                                                      int* __restrict__ row_ptr,
                                                      float* __restrict__ inv) {
  REL_TABLES
  __shared__ u32 vals[CAP];
  __shared__ int outb[CAP];
  __shared__ int rcnt[512];
  __shared__ int roff[512];
  __shared__ int scanbuf[256];
  const int tid = threadIdx.x;
  const int bk = blockIdx.x;
  int r = 0;
#pragma unroll
  for (int i = 1; i < 6; ++i) r += (bk >= BKB[i]);
  int bkloc = bk - BKB[r];
  int r0 = GB[r] + (bkloc << SH[r]);
  int nrows = min(1 << SH[r], ND[r] - (bkloc << SH[r]));
  int p0 = bktbase[bk];
  int p1 = bktbase[bk + 1];
  int n = p1 - p0;
  bool fits = (n <= CAP);

  for (int dl = tid; dl < nrows; dl += 256) rcnt[dl] = 0;
  __syncthreads();
  if (fits) {
    for (int i = tid; i < n; i += 256) {
      u32 v = colbuf2[p0 + i];
      vals[i] = v;
      atomicAdd(&rcnt[v >> 18], 1);
    }
  } else {
    for (int i = tid; i < n; i += 256) {
      u32 v = colbuf2[p0 + i];
      atomicAdd(&rcnt[v >> 18], 1);
    }
  }
  __syncthreads();

  int d0 = tid * 2, d1 = tid * 2 + 1;
  int c0 = (d0 < nrows) ? rcnt[d0] : 0;
  int c1 = (d1 < nrows) ? rcnt[d1] : 0;
  int own = c0 + c1;
  scanbuf[tid] = own;
  __syncthreads();
  for (int o = 1; o < 256; o <<= 1) {
    int v = (tid >= o) ? scanbuf[tid - o] : 0;
    __syncthreads();
    scanbuf[tid] += v;
    __syncthreads();
  }
  int run = scanbuf[tid] - own;
  if (d0 < nrows) {
    roff[d0] = run;
    row_ptr[r0 + d0] = p0 + run;
    inv[r0 + d0] = 1.0f / (float)(c0 > 1 ? c0 : 1);
  }
  if (d1 < nrows) {
    roff[d1] = run + c0;
    row_ptr[r0 + d1] = p0 + run + c0;
    inv[r0 + d1] = 1.0f / (float)(c1 > 1 ? c1 : 1);
  }
  __syncthreads();

  if (fits) {
    for (int i = tid; i < n; i += 256) {
      u32 v = vals[i];
      int dl = v >> 18;
      int pos = atomicAdd(&roff[dl], 1);
      outb[pos] = (int)(v & 0x3FFFFu);
    }
    __syncthreads();
    for (int i = tid; i < n; i += 256) colbuf[p0 + i] = outb[i];
  } else {
    for (int i = tid; i < n; i += 256) {
      u32 v = colbuf2[p0 + i];
      int dl = v >> 18;
      int pos = atomicAdd(&roff[dl], 1);
      colbuf[p0 + pos] = (int)(v & 0x3FFFFu);
    }
  }
}

// ---------------- degree-sort (65 classes, descending) ----------------
__global__ __launch_bounds__(256) void dhist_kernel(const int* __restrict__ row_ptr,
                                                    int* __restrict__ clscnt) {
  __shared__ int h[65];
  int tid = threadIdx.x;
  if (tid < 65) h[tid] = 0;
  __syncthreads();
  int base = blockIdx.x * 1024 + tid * 4;
#pragma unroll
  for (int i = 0; i < 4; ++i) {
    int g = base + i;
    if (g < G_TOT) {
      int d = row_ptr[g + 1] - row_ptr[g];
      int c = 64 - (d < 64 ? d : 64);
      atomicAdd(&h[c], 1);
    }
  }
  __syncthreads();
  if (tid < 65 && h[tid]) atomicAdd(&clscnt[tid], h[tid]);
}

__global__ void dscan_kernel(const int* __restrict__ clscnt, int* __restrict__ clscur) {
  if (threadIdx.x == 0) {
    int run = 0;
    for (int c = 0; c < 65; ++c) {
      clscur[c] = run;
      run += clscnt[c];
    }
  }
}

__global__ __launch_bounds__(256) void dscatter_kernel(const int* __restrict__ row_ptr,
                                                       const float* __restrict__ inv,
                                                       int* __restrict__ clscur,
                                                       uint4* __restrict__ descs) {
  constexpr int GBp[7] = {0, 50000, 150000, 250000, 300000, 301000, 351000};
  __shared__ int h[65], bas[65], cur[65];
  int tid = threadIdx.x;
  if (tid < 65) h[tid] = 0;
  __syncthreads();
  int base = blockIdx.x * 1024 + tid * 4;
  int cls[4];
#pragma unroll
  for (int i = 0; i < 4; ++i) {
    int g = base + i;
    cls[i] = -1;
    if (g < G_TOT) {
      int d = row_ptr[g + 1] - row_ptr[g];
      int c = 64 - (d < 64 ? d : 64);
      cls[i] = c;
      atomicAdd(&h[c], 1);
    }
  }
  __syncthreads();
  if (tid < 65) {
    bas[tid] = h[tid] ? atomicAdd(&clscur[tid], h[tid]) : 0;
    cur[tid] = 0;
  }
  __syncthreads();
#pragma unroll
  for (int i = 0; i < 4; ++i) {
    int g = base + i;
    if (g < G_TOT) {
      int c = cls[i];
      int p = bas[c] + atomicAdd(&cur[c], 1);
      int s = row_ptr[g];
      int cnt = row_ptr[g + 1] - s;
      int r = 0;
#pragma unroll
      for (int k = 1; k < 6; ++k) r += (g >= GBp[k]);
      uint4 d;
      d.x = (u32)s;
      d.y = (u32)cnt | ((u32)r << 24);
      d.z = (u32)(g - GBp[r]);
      d.w = __float_as_uint(inv[g]);
      descs[p] = d;
    }
  }
}

// ---------------- merged prep: 3 casts + 6 weight preps, one launch -------
struct PrepArgs {
  const float* xu; const float* xb; const float* xc;
  const float* W1l; const float* W1r; const float* b1;
  const float* W2l; const float* W2r; const float* b2;
  u16* A1u; u16* A1b; u16* A1c;
  u16* B1u; u16* B1b; u16* B1c;
  u16* B2u; u16* B2b; u16* B2c;
  float* biasbuf;
};

__device__ __forceinline__ void do_cast(const float* __restrict__ x, u16* __restrict__ aself,
                                        int K, int N, int t) {
  if (t >= N * 32) return;
  int row = t >> 5, q = t & 31;
  float4 v = ((const float4*)(x + (size_t)row * 128))[q];
  ushort4 o;
  o.x = f2bf(v.x); o.y = f2bf(v.y); o.z = f2bf(v.z); o.w = f2bf(v.w);
  ((ushort4*)(aself + (size_t)row * K))[q] = o;
}

__device__ __forceinline__ void do_wprep(const float* __restrict__ Wl, const float* __restrict__ Wr,
                                         const float* __restrict__ bsrc, int rx, int ry, int rz,
                                         int nrel, int K, u16* __restrict__ Bcat,
                                         float* __restrict__ bias, int t) {
  int total = 128 * K;
  if (t < total) {
    int o = t / K, k = t - o * K;
    int j = k >> 7, d = k & 127;
    float val;
    if (j < nrel) {
      int rel = (j == 0) ? rx : ((j == 1) ? ry : rz);
      val = Wl[rel * 16384 + o * 128 + d];
    } else {
      val = 0.f;
      if (nrel > 0) val += Wr[rx * 16384 + o * 128 + d];
      if (nrel > 1) val += Wr[ry * 16384 + o * 128 + d];
      if (nrel > 2) val += Wr[rz * 16384 + o * 128 + d];
    }
    Bcat[t] = f2bf(val);
  }
  if (t < 128) {
    float s = 0.f;
    if (nrel > 0) s += bsrc[rx * 128 + t];
    if (nrel > 1) s += bsrc[ry * 128 + t];
    if (nrel > 2) s += bsrc[rz * 128 + t];
    bias[t] = s;
  }
}

// block ranges
#define PB_CU 0
#define PB_CB 12500
#define PB_CC 18750
#define PB_W1U 18875
#define PB_W1B 19067
#define PB_W1C 19323
#define PB_W2U 19451
#define PB_W2B 19643
#define PB_W2C 19899
#define PB_END 20027

__global__ __launch_bounds__(256) void prep_kernel(PrepArgs a) {
  int b = blockIdx.x;
  int tid = threadIdx.x;
  if (b < PB_CB) {
    do_cast(a.xu, a.A1u + SELF_U, KU, NU, (b - PB_CU) * 256 + tid);
  } else if (b < PB_CC) {
    do_cast(a.xb, a.A1b + SELF_B, KB, NB, (b - PB_CB) * 256 + tid);
  } else if (b < PB_W1U) {
    do_cast(a.xc, a.A1c + SELF_C, KC, NC, (b - PB_CC) * 256 + tid);
  } else if (b < PB_W1B) {
    do_wprep(a.W1l, a.W1r, a.b1, 1, 2, 0, 2, KU, a.B1u, a.biasbuf + 0 * 128, (b - PB_W1U) * 256 + tid);
  } else if (b < PB_W1C) {
    do_wprep(a.W1l, a.W1r, a.b1, 0, 3, 5, 3, KB, a.B1b, a.biasbuf + 1 * 128, (b - PB_W1B) * 256 + tid);
  } else if (b < PB_W2U) {
    do_wprep(a.W1l, a.W1r, a.b1, 4, 4, 4, 1, KC, a.B1c, a.biasbuf + 2 * 128, (b - PB_W1C) * 256 + tid);
  } else if (b < PB_W2B) {
    do_wprep(a.W2l, a.W2r, a.b2, 1, 2, 0, 2, KU, a.B2u, a.biasbuf + 3 * 128, (b - PB_W2U) * 256 + tid);
  } else if (b < PB_W2C) {
    do_wprep(a.W2l, a.W2r, a.b2, 0, 3, 5, 3, KB, a.B2b, a.biasbuf + 4 * 128, (b - PB_W2B) * 256 + tid);
  } else {
    do_wprep(a.W2l, a.W2r, a.b2, 4, 4, 4, 1, KC, a.B2c, a.biasbuf + 5 * 128, (b - PB_W2C) * 256 + tid);
  }
}

// ---------------- pull aggregation (unchanged) ----------------
__global__ __launch_bounds__(256) void pull_kernel(const int* __restrict__ colbuf,
                                                   const uint4* __restrict__ descs,
                                                   PullMeta pm) {
  const int l16 = threadIdx.x & 15;
  const int gbase = (threadIdx.x & 63) & ~15;

  for (int idx = blockIdx.x * 16 + (threadIdx.x >> 4); idx < G_TOT; idx += PULL_GRID * 16) {
    uint4 d = descs[idx];
    int s = (int)d.x;
    int cntAll = (int)(d.y & 0xFFFFFFu);
    int r = (int)(d.y >> 24);
    int dstIdx = (int)d.z;
    float sc = __uint_as_float(d.w);
    int e = s + cntAll;
    const uint4* sb = (const uint4*)pm.src[r];
    const int skv = pm.srcK[r] >> 3;

    float a0 = 0.f, a1 = 0.f, a2 = 0.f, a3 = 0.f, a4 = 0.f, a5 = 0.f, a6 = 0.f, a7 = 0.f;
#define ACC8(v)                                      \
    a0 += bf_lo((v).x); a1 += bf_hi((v).x);          \
    a2 += bf_lo((v).y); a3 += bf_hi((v).y);          \
    a4 += bf_lo((v).z); a5 += bf_hi((v).z);          \
    a6 += bf_lo((v).w); a7 += bf_hi((v).w);

    for (int c0 = s; c0 < e; c0 += 16) {
      int cnt = e - c0;
      if (cnt > 16) cnt = 16;
      int myIdx = (l16 < cnt) ? colbuf[c0 + l16] : 0;
      int j = 0;
      for (; j + 8 <= cnt; j += 8) {
        uint4 v[8];
#pragma unroll
        for (int q = 0; q < 8; ++q) {
          int i0 = __shfl(myIdx, gbase + j + q);
          v[q] = sb[(size_t)i0 * skv + l16];
        }
#pragma unroll
        for (int q = 0; q < 8; ++q) { ACC8(v[q]) }
      }
      if (j + 4 <= cnt) {
        uint4 v[4];
#pragma unroll
        for (int q = 0; q < 4; ++q) {
          int i0 = __shfl(myIdx, gbase + j + q);
          v[q] = sb[(size_t)i0 * skv + l16];
        }
#pragma unroll
        for (int q = 0; q < 4; ++q) { ACC8(v[q]) }
        j += 4;
      }
      if (j + 2 <= cnt) {
        uint4 v[2];
#pragma unroll
        for (int q = 0; q < 2; ++q) {
          int i0 = __shfl(myIdx, gbase + j + q);
          v[q] = sb[(size_t)i0 * skv + l16];
        }
#pragma unroll
        for (int q = 0; q < 2; ++q) { ACC8(v[q]) }
        j += 2;
      }
      if (j < cnt) {
        int i0 = __shfl(myIdx, gbase + j);
        uint4 v0 = sb[(size_t)i0 * skv + l16];
        ACC8(v0)
      }
    }
#undef ACC8
    uint4 o;
    o.x = (u32)f2bf(a0 * sc) | ((u32)f2bf(a1 * sc) << 16);
    o.y = (u32)f2bf(a2 * sc) | ((u32)f2bf(a3 * sc) << 16);
    o.z = (u32)f2bf(a4 * sc) | ((u32)f2bf(a5 * sc) << 16);
    o.w = (u32)f2bf(a6 * sc) | ((u32)f2bf(a7 * sc) << 16);
    ((uint4*)(pm.dst[r] + (size_t)dstIdx * pm.dstK[r]))[l16] = o;
  }
}

// ---------------- merged bf16 MFMA GEMM ----------------
// 128x128 tile, 512 threads = 8 waves in a 4(M)x2(N) grid; each wave 32x64
// (acc[2][4] = 32 VGPR -> low register pressure -> 24 waves/CU with 48KB LDS).
// 3-stage counted-vmcnt pipeline (proven structure from the 88us version).
typedef __attribute__((ext_vector_type(8))) short bf16x8;
typedef __attribute__((ext_vector_type(4))) float f32x4;

#define GLOAD16(g, l)                                                              \
  __builtin_amdgcn_global_load_lds((const __attribute__((address_space(1))) void*)(g), \
                                   (__attribute__((address_space(3))) void*)(l), 16, 0, 0)

struct G3 {
  const u16* A[3];
  const u16* B[3];
  const float* bias[3];
  int M[3];
  int K[3];
  u16* outBf[3];
  int outStride[3];
  int outOff[3];
  float* outF;
  long long outBase[3];
  int outF32;
  int blkStart1;
  int blkStart2;
};

// bank-swizzle: rows 0..7 cover all 32 banks at a fixed 16B slot (2-way alias r/r+8 free)
__device__ __forceinline__ int swz(int row) {
  return (((row & 3) ^ ((row >> 2) & 1)) << 4);
}

// stage a 128x32 bf16 tile (8KB): one 1KB chunk per wave (8 waves).
// Linear LDS dest + inverse-swizzled global source (XOR involution, rule #21).
__device__ __forceinline__ void stage8(const u16* __restrict__ M, long long rowBase,
                                       int K, int k0, char* ldsBase, int w, int lane) {
  int row = w * 16 + (lane >> 2);
  int scol = ((lane & 3) * 16) ^ swz(row);
  const char* g = (const char*)M + ((rowBase + row) * (long long)K + k0) * 2 + scol;
  GLOAD16(g, ldsBase + w * 1024 + lane * 16);
}

__global__ __launch_bounds__(512, 6) void gemm3_kernel(G3 a) {
  __shared__ char lds[3 * 16384];  // 3 stages x (A 8KB + B 8KB) = 48KB -> 3 blocks/CU
  const int tid = threadIdx.x;
  const int lane = tid & 63;
  const int w = tid >> 6;   // 0..7
  const int wr = w >> 1;    // 0..3 row-group (32 rows each)
  const int wc = w & 1;     // 0..1 col-group (64 cols each)
  int b = blockIdx.x;
  int j = (b >= a.blkStart2) ? 2 : ((b >= a.blkStart1) ? 1 : 0);
  int bloc = b - (j == 2 ? a.blkStart2 : (j == 1 ? a.blkStart1 : 0));
  const long long rowBase = (long long)bloc * 128;
  const u16* A = a.A[j];
  const u16* B = a.B[j];
  const int K = a.K[j];
  const int M = a.M[j];
  const int nk = K >> 5;  // K/32 steps: 12 / 16 / 8

  f32x4 acc[2][4];
#pragma unroll
  for (int m = 0; m < 2; ++m)
#pragma unroll
    for (int n = 0; n < 4; ++n) acc[m][n] = (f32x4){0.f, 0.f, 0.f, 0.f};

  // prologue: prefetch stages 0,1 (2 loads/wave each)
  stage8(A, rowBase, K, 0, lds + 0 * 16384, w, lane);
  stage8(B, 0, K, 0, lds + 0 * 16384 + 8192, w, lane);
  if (nk > 1) {
    stage8(A, rowBase, K, 32, lds + 1 * 16384, w, lane);
    stage8(B, 0, K, 32, lds + 1 * 16384 + 8192, w, lane);
  }

  const int cb = (lane >> 4) * 16;
  const int rA0 = wr * 32 + (lane & 15);
  const int rB0 = wc * 64 + (lane & 15);

  for (int k = 0; k < nk; ++k) {
    // issue stage k+2 (into buffer freed at end of step k-1)
    if (k + 2 < nk) {
      int sb2 = ((k + 2) % 3) * 16384;
      stage8(A, rowBase, K, (k + 2) * 32, lds + sb2, w, lane);
      stage8(B, 0, K, (k + 2) * 32, lds + sb2 + 8192, w, lane);
      asm volatile("s_waitcnt vmcnt(4)" ::: "memory");  // stage k landed; k+1,k+2 in flight
    } else if (k + 1 < nk) {
      asm volatile("s_waitcnt vmcnt(2)" ::: "memory");  // stage k landed; k+1 in flight
    } else {
      asm volatile("s_waitcnt vmcnt(0)" ::: "memory");  // last stage
    }
    __builtin_amdgcn_s_barrier();  // all waves' stage-k loads are in LDS
    asm volatile("" ::: "memory");

    const char* SA = lds + (k % 3) * 16384;
    const char* SB = SA + 8192;
    bf16x8 af[2], bfr[4];
#pragma unroll
    for (int m = 0; m < 2; ++m) {
      int rr = rA0 + m * 16;
      af[m] = *(const bf16x8*)(SA + rr * 64 + (cb ^ swz(rr)));
    }
#pragma unroll
    for (int n = 0; n < 4; ++n) {
      int rr = rB0 + n * 16;
      bfr[n] = *(const bf16x8*)(SB + rr * 64 + (cb ^ swz(rr)));
    }
    __builtin_amdgcn_s_setprio(1);
#pragma unroll
    for (int m = 0; m < 2; ++m)
#pragma unroll
      for (int n = 0; n < 4; ++n)
        acc[m][n] = __builtin_amdgcn_mfma_f32_16x16x32_bf16(af[m], bfr[n], acc[m][n], 0, 0, 0);
    __builtin_amdgcn_s_setprio(0);

    asm volatile("" ::: "memory");
    __builtin_amdgcn_s_barrier();  // buf k fully read before stage k+3 overwrites it
    asm volatile("" ::: "memory");
  }

  const float* bias = a.bias[j];
  const int colBase = lane & 15;
#pragma unroll
  for (int m = 0; m < 2; ++m) {
    long long r0 = rowBase + wr * 32 + m * 16 + ((lane >> 4) * 4);
#pragma unroll
    for (int n = 0; n < 4; ++n) {
      int col = wc * 64 + n * 16 + colBase;
      float bv = bias[col];
#pragma unroll
      for (int q = 0; q < 4; ++q) {
        long long row = r0 + q;
        if (row < M) {
          float v = acc[m][n][q] + bv;
          v = v > 0.f ? v : 0.f;
          if (a.outF32)
            a.outF[a.outBase[j] + row * 128 + col] = v;
          else
            a.outBf[j][row * (long long)a.outStride[j] + a.outOff[j] + col] = f2bf(v);
        }
      }
    }
  }
}

// ---------------- host launcher ----------------
extern "C" void kernel_launch(void* const* d_in, const int* in_sizes, int n_in,
                              void* d_out, int out_size, void* d_ws, size_t ws_size,
                              hipStream_t stream) {
  const float* xu = (const float*)d_in[0];
  const float* xb = (const float*)d_in[1];
  const float* xc = (const float*)d_in[2];
  const float* W1l = (const float*)d_in[3];
  const float* b1 = (const float*)d_in[4];
  const float* W1r = (const float*)d_in[5];
  const float* W2l = (const float*)d_in[6];
  const float* b2 = (const float*)d_in[7];
  const float* W2r = (const float*)d_in[8];
  EdgePtrs ep;
  ep.p[0] = (const int*)d_in[9];
  ep.p[1] = (const int*)d_in[10];
  ep.p[2] = (const int*)d_in[11];
  ep.p[3] = (const int*)d_in[12];
  ep.p[4] = (const int*)d_in[13];
  ep.p[5] = (const int*)d_in[14];
  float* out = (float*)d_out;

  char* ws = (char*)d_ws;
  size_t off = 0;
  auto alloc = [&](size_t b) {
    char* p = ws + off;
    off = (off + b + 255) & ~(size_t)255;
    return p;
  };

  int* row_ptr = (int*)alloc((size_t)(G_TOT + 1) * 4);
  float* inv = (float*)alloc((size_t)G_TOT * 4);
  int* colbuf = (int*)alloc((size_t)E_TOT * 4);
  u32* colbuf2 = (u32*)alloc((size_t)E_TOT * 4);
  int* gcursor = (int*)alloc((size_t)NBKT * 4);
  int* bktcnt = (int*)alloc((size_t)NBKT * 4);
  int* bktbase = (int*)alloc((size_t)(NBKT + 1) * 4);
  uint4* descs = (uint4*)alloc((size_t)G_TOT * 16);
  int* clsbuf = (int*)alloc(130 * 4);
  u16* A1u = (u16*)alloc((size_t)MU_PAD * KU * 2);
  u16* A1b = (u16*)alloc((size_t)MB_PAD * KB * 2);
  u16* A1c = (u16*)alloc((size_t)MC_PAD * KC * 2);
  u16* A2u = (u16*)alloc((size_t)MU_PAD * KU * 2);
  u16* A2b = (u16*)alloc((size_t)MB_PAD * KB * 2);
  u16* A2c = (u16*)alloc((size_t)MC_PAD * KC * 2);
  u16* B1u = (u16*)alloc((size_t)128 * KU * 2);
  u16* B1b = (u16*)alloc((size_t)128 * KB * 2);
  u16* B1c = (u16*)alloc((size_t)128 * KC * 2);
  u16* B2u = (u16*)alloc((size_t)128 * KU * 2);
  u16* B2b = (u16*)alloc((size_t)128 * KB * 2);
  u16* B2c = (u16*)alloc((size_t)128 * KC * 2);
  float* biasbuf = (float*)alloc(6 * 128 * 4);

  // CSR build
  hipMemsetAsync(bktcnt, 0, (size_t)NBKT * 4, stream);
  hipMemsetAsync(clsbuf, 0, 130 * 4, stream);
  bhist_kernel<<<(E_TOT + 16383) / 16384, 256, 0, stream>>>(ep, bktcnt);
  bscan_kernel<<<1, 256, 0, stream>>>(bktcnt, bktbase, gcursor, row_ptr);
  bucket1_kernel<<<(E_TOT + CAP - 1) / CAP, 256, 0, stream>>>(ep, gcursor, colbuf2);
  bucket2_kernel<<<NBKT, 256, 0, stream>>>(bktbase, colbuf2, colbuf, row_ptr, inv);

  // degree sort -> sequential descriptors
  int nblk = (G_TOT + 1023) / 1024;
  dhist_kernel<<<nblk, 256, 0, stream>>>(row_ptr, clsbuf);
  dscan_kernel<<<1, 64, 0, stream>>>(clsbuf, clsbuf + 65);
  dscatter_kernel<<<nblk, 256, 0, stream>>>(row_ptr, inv, clsbuf + 65, descs);

  // merged prep (casts + weight concats)
  PrepArgs pa;
  pa.xu = xu; pa.xb = xb; pa.xc = xc;
  pa.W1l = W1l; pa.W1r = W1r; pa.b1 = b1;
  pa.W2l = W2l; pa.W2r = W2r; pa.b2 = b2;
  pa.A1u = A1u; pa.A1b = A1b; pa.A1c = A1c;
  pa.B1u = B1u; pa.B1b = B1b; pa.B1c = B1c;
  pa.B2u = B2u; pa.B2b = B2b; pa.B2c = B2c;
  pa.biasbuf = biasbuf;
  prep_kernel<<<PB_END, 256, 0, stream>>>(pa);

  // ---- layer 1 ----
  PullMeta pm1;
  pm1.src[0] = A1u + SELF_U; pm1.srcK[0] = KU; pm1.dst[0] = A1b + 0;   pm1.dstK[0] = KB;
  pm1.src[1] = A1b + SELF_B; pm1.srcK[1] = KB; pm1.dst[1] = A1u + 0;   pm1.dstK[1] = KU;
  pm1.src[2] = A1u + SELF_U; pm1.srcK[2] = KU; pm1.dst[2] = A1u + 128; pm1.dstK[2] = KU;
  pm1.src[3] = A1b + SELF_B; pm1.srcK[3] = KB; pm1.dst[3] = A1b + 128; pm1.dstK[3] = KB;
  pm1.src[4] = A1b + SELF_B; pm1.srcK[4] = KB; pm1.dst[4] = A1c + 0;   pm1.dstK[4] = KC;
  pm1.src[5] = A1c + SELF_C; pm1.srcK[5] = KC; pm1.dst[5] = A1b + 256; pm1.dstK[5] = KB;
  pull_kernel<<<PULL_GRID, 256, 0, stream>>>(colbuf, descs, pm1);

  G3 g1;
  g1.A[0] = A1u; g1.A[1] = A1b; g1.A[2] = A1c;
  g1.B[0] = B1u; g1.B[1] = B1b; g1.B[2] = B1c;
  g1.bias[0] = biasbuf + 0 * 128; g1.bias[1] = biasbuf + 1 * 128; g1.bias[2] = biasbuf + 2 * 128;
  g1.M[0] = NU; g1.M[1] = NB; g1.M[2] = NC;
  g1.K[0] = KU; g1.K[1] = KB; g1.K[2] = KC;
  g1.outBf[0] = A2u; g1.outBf[1] = A2b; g1.outBf[2] = A2c;
  g1.outStride[0] = KU; g1.outStride[1] = KB; g1.outStride[2] = KC;
  g1.outOff[0] = SELF_U; g1.outOff[1] = SELF_B; g1.outOff[2] = SELF_C;
  g1.outF = nullptr;
  g1.outBase[0] = g1.outBase[1] = g1.outBase[2] = 0;
  g1.outF32 = 0;
  g1.blkStart1 = MU_PAD / 128;
  g1.blkStart2 = MU_PAD / 128 + MB_PAD / 128;
  gemm3_kernel<<<MU_PAD / 128 + MB_PAD / 128 + MC_PAD / 128, 512, 0, stream>>>(g1);

  // ---- layer 2 ----
  PullMeta pm2;
  pm2.src[0] = A2u + SELF_U; pm2.srcK[0] = KU; pm2.dst[0] = A2b + 0;   pm2.dstK[0] = KB;
  pm2.src[1] = A2b + SELF_B; pm2.srcK[1] = KB; pm2.dst[1] = A2u + 0;   pm2.dstK[1] = KU;
  pm2.src[2] = A2u + SELF_U; pm2.srcK[2] = KU; pm2.dst[2] = A2u + 128; pm2.dstK[2] = KU;
  pm2.src[3] = A2b + SELF_B; pm2.srcK[3] = KB; pm2.dst[3] = A2b + 128; pm2.dstK[3] = KB;
  pm2.src[4] = A2b + SELF_B; pm2.srcK[4] = KB; pm2.dst[4] = A2c + 0;   pm2.dstK[4] = KC;
  pm2.src[5] = A2c + SELF_C; pm2.srcK[5] = KC; pm2.dst[5] = A2b + 256; pm2.dstK[5] = KB;
  pull_kernel<<<PULL_GRID, 256, 0, stream>>>(colbuf, descs, pm2);

  G3 g2;
  g2.A[0] = A2u; g2.A[1] = A2b; g2.A[2] = A2c;
  g2.B[0] = B2u; g2.B[1] = B2b; g2.B[2] = B2c;
  g2.bias[0] = biasbuf + 3 * 128; g2.bias[1] = biasbuf + 4 * 128; g2.bias[2] = biasbuf + 5 * 128;
  g2.M[0] = NU; g2.M[1] = NB; g2.M[2] = NC;
  g2.K[0] = KU; g2.K[1] = KB; g2.K[2] = KC;
  g2.outBf[0] = g2.outBf[1] = g2.outBf[2] = nullptr;
  g2.outStride[0] = g2.outStride[1] = g2.outStride[2] = 0;
  g2.outOff[0] = g2.outOff[1] = g2.outOff[2] = 0;
  g2.outF = out;
  g2.outBase[0] = 0;
  g2.outBase[1] = (long long)NU * 128;
  g2.outBase[2] = (long long)(NU + NB) * 128;
  g2.outF32 = 1;
  g2.blkStart1 = MU_PAD / 128;
  g2.blkStart2 = MU_PAD / 128 + MB_PAD / 128;
  gemm3_kernel<<<MU_PAD / 128 + MB_PAD / 128 + MC_PAD / 128, 512, 0, stream>>>(g2);
}